// Round 1
// baseline (168.919 us; speedup 1.0000x reference)
//
#include <hip/hip_runtime.h>

typedef __attribute__((ext_vector_type(8))) short bf16x8;
typedef __attribute__((ext_vector_type(4))) float f32x4;
typedef __attribute__((ext_vector_type(4))) unsigned int u32x4;

#define HW_ (128 * 128)

__device__ __forceinline__ unsigned short f2bf(float f) {
  unsigned int u = __builtin_bit_cast(unsigned int, f);
  u += 0x7fffu + ((u >> 16) & 1u);
  return (unsigned short)(u >> 16);
}

// weight (64,64,3,3) f32  ->  wb[p][o][c] bf16   (36864 elems, 72 KB in d_ws)
__global__ __launch_bounds__(256) void prep_w(const float* __restrict__ w,
                                              unsigned short* __restrict__ wb) {
  int t = blockIdx.x * 256 + threadIdx.x;   // < 36864
  int p = t >> 12;
  int rem = t & 4095;
  int o = rem >> 6, c = rem & 63;
  wb[t] = f2bf(w[(o * 64 + c) * 9 + p]);
}

__global__ __launch_bounds__(256) void pac_main(
    const float* __restrict__ x, const float* __restrict__ g,
    const unsigned short* __restrict__ wb, const float* __restrict__ bias,
    float* __restrict__ out) {
  // x tile: [rr=3][cc=66][c=64 padded to 72] bf16 -> 144B rows (2-way LDS alias only)
  __shared__ __align__(16) unsigned short xlds[3 * 66 * 72];
  __shared__ float glds[16 * 3 * 66];   // guide tile f32
  __shared__ float klds[9 * 64];        // bilateral kernel weights

  const int tid = threadIdx.x;
  const int w0 = (blockIdx.x & 1) * 64;
  const int h = blockIdx.y;
  const int b = blockIdx.z;

  // ---- stage guide tile: glds[(cg*3+rr)*66+cc] = guide[b][cg][h-1+rr][w0-1+cc]
  for (int e = tid; e < 16 * 3 * 66; e += 256) {
    int cg = e / 198;
    int rem = e - cg * 198;
    int rr = rem / 66;
    int cc = rem - rr * 66;
    int gh = h - 1 + rr, gw = w0 - 1 + cc;
    float v = 0.f;
    if ((unsigned)gh < 128u && (unsigned)gw < 128u)
      v = g[((b * 16 + cg) * 128 + gh) * 128 + gw];
    glds[e] = v;
  }

  // ---- stage x tile as bf16: per (rr,cc) write 8-channel chunks (16B ds_write)
  for (int fe = tid; fe < 1584; fe += 256) {   // 1584 = 3*66*8 chunks
    int rc = fe >> 3, chunk = fe & 7;
    int rr = rc / 66, cc = rc - rr * 66;
    int gh = h - 1 + rr, gw = w0 - 1 + cc;
    bool ok = ((unsigned)gh < 128u) && ((unsigned)gw < 128u);
    const float* xs = x + (((size_t)b * 64 + chunk * 8) * 128 + (ok ? gh : 0)) * 128 + (ok ? gw : 0);
    unsigned short v[8];
#pragma unroll
    for (int u = 0; u < 8; ++u) {
      float f = ok ? xs[u * HW_] : 0.f;
      v[u] = f2bf(f);
    }
    *reinterpret_cast<u32x4*>(&xlds[rc * 72 + chunk * 8]) =
        *reinterpret_cast<const u32x4*>(v);
  }
  __syncthreads();

  // ---- bilateral kernel: klds[p*64+m] = exp(-0.5 * sum_cg (g_tap - g_ctr)^2)
  for (int e = tid; e < 576; e += 256) {
    int p = e >> 6, m = e & 63;
    int di = p / 3, dj = p - di * 3;
    float s = 0.f;
#pragma unroll
    for (int cg = 0; cg < 16; ++cg) {
      float a = glds[(cg * 3 + di) * 66 + m + dj];
      float c = glds[(cg * 3 + 1) * 66 + m + 1];
      float d = a - c;
      s += d * d;
    }
    klds[e] = __expf(-0.5f * s);
  }
  __syncthreads();

  // ---- MFMA main loop: D[o][m] ; A = weights (o x c), B = x pixels (c x m)
  const int wv = tid >> 6, l = tid & 63;
  const int wave_m = wv & 1, wave_n = wv >> 1;
  const int l15 = l & 15, lhi = l >> 4;

  f32x4 acc[2][2];
#pragma unroll
  for (int i = 0; i < 2; ++i)
#pragma unroll
    for (int j = 0; j < 2; ++j) acc[i][j] = (f32x4){0.f, 0.f, 0.f, 0.f};

#pragma unroll
  for (int p = 0; p < 9; ++p) {
    const int di = p / 3, dj = p - (p / 3) * 3;
    f32x4 tmp[2][2];
#pragma unroll
    for (int i = 0; i < 2; ++i)
#pragma unroll
      for (int j = 0; j < 2; ++j) tmp[i][j] = (f32x4){0.f, 0.f, 0.f, 0.f};

#pragma unroll
    for (int kk = 0; kk < 2; ++kk) {
      const int c0 = kk * 32 + lhi * 8;
      bf16x8 xf[2], wf[2];
#pragma unroll
      for (int ff = 0; ff < 2; ++ff) {
        const int m = wave_m * 32 + ff * 16 + l15;
        xf[ff] = *reinterpret_cast<const bf16x8*>(&xlds[(di * 66 + m + dj) * 72 + c0]);
        const int o = wave_n * 32 + ff * 16 + l15;
        wf[ff] = *reinterpret_cast<const bf16x8*>(&wb[(p * 64 + o) * 64 + c0]);
      }
#pragma unroll
      for (int fr = 0; fr < 2; ++fr)
#pragma unroll
        for (int fc = 0; fc < 2; ++fc)
          tmp[fr][fc] = __builtin_amdgcn_mfma_f32_16x16x32_bf16(
              wf[fr], xf[fc], tmp[fr][fc], 0, 0, 0);
    }
    // fold per-pixel bilateral weight into f32 master accumulators
    const float km0 = klds[p * 64 + wave_m * 32 + l15];
    const float km1 = klds[p * 64 + wave_m * 32 + 16 + l15];
#pragma unroll
    for (int fr = 0; fr < 2; ++fr)
#pragma unroll
      for (int j = 0; j < 4; ++j) {
        acc[fr][0][j] += km0 * tmp[fr][0][j];
        acc[fr][1][j] += km1 * tmp[fr][1][j];
      }
  }

  // ---- epilogue: bias + relu, coalesced stores (cols = pixels)
#pragma unroll
  for (int fr = 0; fr < 2; ++fr)
#pragma unroll
    for (int j = 0; j < 4; ++j) {
      const int o = wave_n * 32 + fr * 16 + lhi * 4 + j;
      const float bv = bias[o];
#pragma unroll
      for (int fc = 0; fc < 2; ++fc) {
        const int m = wave_m * 32 + fc * 16 + l15;
        float v = acc[fr][fc][j] + bv;
        out[(((size_t)b * 64 + o) * 128 + h) * 128 + w0 + m] = v > 0.f ? v : 0.f;
      }
    }
}

extern "C" void kernel_launch(void* const* d_in, const int* in_sizes, int n_in,
                              void* d_out, int out_size, void* d_ws, size_t ws_size,
                              hipStream_t stream) {
  const float* x = (const float*)d_in[0];
  const float* guide = (const float*)d_in[1];
  const float* weight = (const float*)d_in[2];
  const float* bias = (const float*)d_in[3];
  float* out = (float*)d_out;
  unsigned short* wb = (unsigned short*)d_ws;  // 73728 bytes

  hipLaunchKernelGGL(prep_w, dim3(36864 / 256), dim3(256), 0, stream, weight, wb);
  hipLaunchKernelGGL(pac_main, dim3(2, 128, 8), dim3(256), 0, stream,
                     x, guide, wb, bias, out);
}